// Round 6
// baseline (1819.182 us; speedup 1.0000x reference)
//
#include <hip/hip_runtime.h>

#define NN 20000
#define NE 640000

typedef __attribute__((ext_vector_type(4))) float f4;
typedef __attribute__((ext_vector_type(8))) unsigned short us8;
typedef __attribute__((ext_vector_type(8))) __bf16 bf8;
typedef __attribute__((ext_vector_type(4))) int i4;

__device__ __forceinline__ unsigned short f2bf(float f) {
    union { float f; unsigned int u; } v; v.f = f;
    unsigned int u = v.u;
    return (unsigned short)((u + 0x7FFFu + ((u >> 16) & 1u)) >> 16);
}
__device__ __forceinline__ float bf2f(unsigned short b) {
    union { unsigned int u; float f; } v; v.u = ((unsigned int)b) << 16; return v.f;
}
__device__ __forceinline__ f4 mfma16(us8 a, us8 b, f4 c) {
    return __builtin_amdgcn_mfma_f32_16x16x32_bf16(
        __builtin_bit_cast(bf8, a), __builtin_bit_cast(bf8, b), c, 0, 0, 0);
}
// split 8 fp32 (two f4) into hi/lo bf16 fragments
__device__ __forceinline__ void split8(f4 a0, f4 a1, us8& h, us8& l) {
#pragma unroll
    for (int j = 0; j < 4; j++) {
        unsigned short hb = f2bf(a0[j]); h[j] = hb; l[j] = f2bf(a0[j] - bf2f(hb));
        unsigned short hb2 = f2bf(a1[j]); h[4 + j] = hb2; l[4 + j] = f2bf(a1[j] - bf2f(hb2));
    }
}

// ---------------- weight prep: transpose + bf16 ----------------
__global__ void __launch_bounds__(256) prep_weights(
    const float* __restrict__ eW1, const float* __restrict__ eW2,
    const float* __restrict__ nW1, const float* __restrict__ nW2,
    const float* __restrict__ cW1,
    unsigned short* __restrict__ eW1T, unsigned short* __restrict__ eW2T,
    unsigned short* __restrict__ nW1T, unsigned short* __restrict__ nW2T,
    unsigned short* __restrict__ cW1T, float* __restrict__ ew1last)
{
    int i = blockIdx.x * 256 + threadIdx.x;
    if (i < 32768) { int f = i >> 8, k = i & 255; eW1T[i] = f2bf(eW1[k * 128 + f]); return; }
    i -= 32768;
    if (i < 16384) { int f = i >> 7, k = i & 127; eW2T[i] = f2bf(eW2[k * 128 + f]); return; }
    i -= 16384;
    if (i < 32768) { int f = i >> 8, k = i & 255; nW1T[i] = f2bf(nW1[k * 128 + f]); return; }
    i -= 32768;
    if (i < 16384) { int f = i >> 7, k = i & 127; nW2T[i] = f2bf(nW2[k * 128 + f]); return; }
    i -= 16384;
    if (i < 16384) { int f = i >> 7, k = i & 127; cW1T[i] = f2bf(cW1[k * 128 + f]); return; }
    i -= 16384;
    if (i < 128) { ew1last[i] = eW1[256 * 128 + i]; }
}

// ---------------- embedding + state init ----------------
__global__ void __launch_bounds__(128) embed_init(
    const float* __restrict__ h_in, const float* __restrict__ x_in,
    const float* __restrict__ embW, const float* __restrict__ embB,
    float* __restrict__ h_cur, unsigned short* __restrict__ h_pk,
    float* __restrict__ x_cur, float* __restrict__ m, float* __restrict__ xu)
{
    int n = blockIdx.x, f = threadIdx.x;
    float acc = embB[f];
#pragma unroll
    for (int p = 0; p < 16; p++) acc += h_in[n * 16 + p] * embW[p * 128 + f];
    h_cur[n * 128 + f] = acc;
    unsigned short hh = f2bf(acc);
    h_pk[(size_t)n * 256 + f] = hh;
    h_pk[(size_t)n * 256 + 128 + f] = f2bf(acc - bf2f(hh));
    m[n * 128 + f] = 0.f;
    if (f < 3) { x_cur[n * 3 + f] = x_in[n * 3 + f]; xu[n * 3 + f] = 0.f; }
}

// ---------------- CSR sort: zero / hist / scan / scatter ----------------
__global__ void __launch_bounds__(256) zero_kernel(int* __restrict__ p, int n) {
    int i = blockIdx.x * 256 + threadIdx.x;
    if (i < n) p[i] = 0;
}

__global__ void __launch_bounds__(256) hist_kernel(const int* __restrict__ eidx,
                                                   int* __restrict__ deg) {
    int e = blockIdx.x * 256 + threadIdx.x;
    if (e < NE) atomicAdd(&deg[eidx[e]], 1);
}

__global__ void __launch_bounds__(1024) scan_kernel(const int* __restrict__ deg,
                                                    int* __restrict__ offs) {
    __shared__ int ssum[1024];
    const int t = threadIdx.x;
    const int base = t * 20;
    int loc[20];
    int s = 0;
#pragma unroll
    for (int i = 0; i < 20; i++) {
        int v = (base + i < NN) ? deg[base + i] : 0;
        loc[i] = s; s += v;
    }
    ssum[t] = s;
    __syncthreads();
    for (int d = 1; d < 1024; d <<= 1) {
        int v = (t >= d) ? ssum[t - d] : 0;
        __syncthreads();
        ssum[t] += v;
        __syncthreads();
    }
    int excl = (t == 0) ? 0 : ssum[t - 1];
#pragma unroll
    for (int i = 0; i < 20; i++)
        if (base + i < NN) offs[base + i] = excl + loc[i];
    if (t == 1023) offs[NN] = ssum[1023];
}

__global__ void __launch_bounds__(256) scatter_kernel(
    const int* __restrict__ eidx, const int* __restrict__ offs,
    int* __restrict__ cursor, int* __restrict__ srow, int* __restrict__ scol)
{
    int e = blockIdx.x * 256 + threadIdx.x;
    if (e >= NE) return;
    int r = eidx[e];
    int pos = offs[r] + atomicAdd(&cursor[r], 1);
    srow[pos] = r;
    scol[pos] = eidx[NE + e];
}

// ---------------- fused edge kernel ------------------------------------
// 32 edges/block, 256 threads (4 waves: wm edge-half, wn feat-half).
// A-fragments for GEMM1 loaded per-lane directly from packed hi/lo global h.
// LDS: z1f fp32 [0,16KB) (z3 bf16 overlays it later), e_ij fp32 [16KB,32KB).
__global__ void __launch_bounds__(256, 4) edge_kernel(
    const int* __restrict__ srow, const int* __restrict__ scol,
    const unsigned short* __restrict__ h_pk,
    const float* __restrict__ x_cur,
    const unsigned short* __restrict__ eW1T, const unsigned short* __restrict__ eW2T,
    const unsigned short* __restrict__ cW1T, const float* __restrict__ ew1last,
    const float* __restrict__ eb1, const float* __restrict__ eb2,
    const float* __restrict__ cb1, const float* __restrict__ cb2,
    const float* __restrict__ cW2,
    float* __restrict__ m, float* __restrict__ xu)
{
    __shared__ __align__(16) char sm[32 * 1024];
    __shared__ int rowS[32];
    __shared__ int colS[32];
    __shared__ float rpS[32][3];
    __shared__ float rdS[32];

    const int t = threadIdx.x;
    const int e0 = blockIdx.x * 32;

    if (t < 32) {
        int r = srow[e0 + t], c = scol[e0 + t];
        rowS[t] = r; colS[t] = c;
        float dx = x_cur[r * 3 + 0] - x_cur[c * 3 + 0];
        float dy = x_cur[r * 3 + 1] - x_cur[c * 3 + 1];
        float dz = x_cur[r * 3 + 2] - x_cur[c * 3 + 2];
        rpS[t][0] = dx; rpS[t][1] = dy; rpS[t][2] = dz;
        rdS[t] = dx * dx + dy * dy + dz * dz;
    }
    __syncthreads();

    const int lane = t & 63, w = t >> 6;
    const int wm = w & 1, wn = w >> 1;
    const int lr = lane & 15, lg = lane >> 4;
    const int eA = wm * 16 + lr;      // A-frag row (edge)
    const int eC0 = wm * 16 + lg * 4; // C-frag row base (edge)

    // ---- GEMM1: z1 = relu(edge_feat @ eW1 + eb1 + rd*w_last) ----
    // A-frags direct from global h_pk (hi|lo): k<128 -> h[row], k>=128 -> h[col]
    const int node_r = rowS[eA], node_c = colS[eA];
    us8 afh[8], afl[8];
#pragma unroll
    for (int ks = 0; ks < 8; ks++) {
        int koff = (ks & 3) * 32 + lg * 8;
        const unsigned short* p = h_pk + (size_t)(ks < 4 ? node_r : node_c) * 256 + koff;
        afh[ks] = *reinterpret_cast<const us8*>(p);
        afl[ks] = *reinterpret_cast<const us8*>(p + 128);
    }
    float rd4[4];
#pragma unroll
    for (int r = 0; r < 4; r++) rd4[r] = rdS[eC0 + r];

#pragma unroll
    for (int nt = 0; nt < 4; nt++) {
        int feat = wn * 64 + nt * 16 + lr;
        const unsigned short* bp = eW1T + feat * 256 + lg * 8;
        f4 a = {0.f, 0.f, 0.f, 0.f};
#pragma unroll
        for (int ks = 0; ks < 8; ks++) {
            us8 b = *reinterpret_cast<const us8*>(bp + ks * 32);
            a = mfma16(afh[ks], b, a);
            a = mfma16(afl[ks], b, a);
        }
        float bias = eb1[feat], wl = ew1last[feat];
#pragma unroll
        for (int r = 0; r < 4; r++) {
            float z = a[r] + bias + rd4[r] * wl;
            z = z > 0.f ? z : 0.f;
            int e = eC0 + r;
            int ad = (e * 512 + feat * 4) ^ ((e & 7) << 5);
            *reinterpret_cast<float*>(sm + ad) = z;   // z1f
        }
    }
    __syncthreads();

    // ---- GEMM2: e_ij = z1 @ eW2 + eb2 (A split at read) -> e_ij fp32 LDS ----
    us8 a2h[4], a2l[4];
#pragma unroll
    for (int ks = 0; ks < 4; ks++) {
        int base = (eA * 512 + ks * 128 + lg * 32) ^ ((eA & 7) << 5);
        f4 a0 = *reinterpret_cast<const f4*>(sm + base);
        f4 a1 = *reinterpret_cast<const f4*>(sm + base + 16);
        split8(a0, a1, a2h[ks], a2l[ks]);
    }
#pragma unroll
    for (int nt = 0; nt < 4; nt++) {
        int feat = wn * 64 + nt * 16 + lr;
        const unsigned short* bp = eW2T + feat * 128 + lg * 8;
        f4 a = {0.f, 0.f, 0.f, 0.f};
#pragma unroll
        for (int ks = 0; ks < 4; ks++) {
            us8 b = *reinterpret_cast<const us8*>(bp + ks * 32);
            a = mfma16(a2h[ks], b, a);
            a = mfma16(a2l[ks], b, a);
        }
        float bias = eb2[feat];
#pragma unroll
        for (int r = 0; r < 4; r++) {
            float v = a[r] + bias;
            int e = eC0 + r;
            int ad = 16384 + ((e * 512 + feat * 4) ^ ((e & 7) << 5));
            *reinterpret_cast<float*>(sm + ad) = v;   // e_ij fp32
        }
    }
    __syncthreads();

    // ---- m accumulation: waves 0-1, fp32, run-aggregated atomics ----
    if (t < 128) {
        int feat = t;
        float acc = 0.f;
        int prow = rowS[0];
#pragma unroll
        for (int e = 0; e < 32; e++) {
            int r = rowS[e];
            if (r != prow) {
                atomicAdd(&m[(size_t)prow * 128 + feat], acc);
                acc = 0.f; prow = r;
            }
            int ad = 16384 + ((e * 512 + feat * 4) ^ ((e & 7) << 5));
            acc += *reinterpret_cast<const float*>(sm + ad);
        }
        atomicAdd(&m[(size_t)prow * 128 + feat], acc);
    }

    // ---- GEMM3: z3 = relu(e_ij @ cW1 + cb1), hi-bf16 only (x-path) ----
    us8 af3[4];
#pragma unroll
    for (int ks = 0; ks < 4; ks++) {
        int base = 16384 + ((eA * 512 + ks * 128 + lg * 32) ^ ((eA & 7) << 5));
        f4 a0 = *reinterpret_cast<const f4*>(sm + base);
        f4 a1 = *reinterpret_cast<const f4*>(sm + base + 16);
        us8 h;
#pragma unroll
        for (int j = 0; j < 4; j++) { h[j] = f2bf(a0[j]); h[4 + j] = f2bf(a1[j]); }
        af3[ks] = h;
    }
#pragma unroll
    for (int nt = 0; nt < 4; nt++) {
        int feat = wn * 64 + nt * 16 + lr;
        const unsigned short* bp = cW1T + feat * 128 + lg * 8;
        f4 a = {0.f, 0.f, 0.f, 0.f};
#pragma unroll
        for (int ks = 0; ks < 4; ks++)
            a = mfma16(af3[ks], *reinterpret_cast<const us8*>(bp + ks * 32), a);
        float bias = cb1[feat];
#pragma unroll
        for (int r = 0; r < 4; r++) {
            float z = a[r] + bias;
            z = z > 0.f ? z : 0.f;
            int e = eC0 + r;
            int ad = (e * 256 + feat * 2) ^ ((e & 7) << 4);   // z3 overlays z1f
            *reinterpret_cast<unsigned short*>(sm + ad) = f2bf(z);
        }
    }
    __syncthreads();

    // ---- alpha = z3 @ cW2 + cb2 ; x-update atomics ----
    {
        int e = t >> 3, s = t & 7;
        float sum = 0.f;
#pragma unroll
        for (int hf = 0; hf < 2; hf++) {
            int ad = (e * 256 + s * 32 + hf * 16) ^ ((e & 7) << 4);
            us8 v = *reinterpret_cast<const us8*>(sm + ad);
#pragma unroll
            for (int j = 0; j < 8; j++)
                sum += bf2f((unsigned short)v[j]) * cW2[s * 16 + hf * 8 + j];
        }
        sum += __shfl_xor(sum, 1, 64);
        sum += __shfl_xor(sum, 2, 64);
        sum += __shfl_xor(sum, 4, 64);
        if (s == 0) {
            float alpha = sum + cb2[0];
            int r = rowS[e];
            atomicAdd(&xu[r * 3 + 0], alpha * rpS[e][0]);
            atomicAdd(&xu[r * 3 + 1], alpha * rpS[e][1]);
            atomicAdd(&xu[r * 3 + 2], alpha * rpS[e][2]);
        }
    }
}

// ---------------- node update kernel (fp32 A via hi/lo MFMA) ----------------
// 32 nodes/block, 256 threads
__global__ void __launch_bounds__(256, 4) node_kernel(
    const unsigned short* __restrict__ nW1T, const unsigned short* __restrict__ nW2T,
    const float* __restrict__ nb1, const float* __restrict__ nb2,
    float* __restrict__ h_cur, unsigned short* __restrict__ h_pk,
    float* __restrict__ m, float* __restrict__ x_cur, float* __restrict__ xu)
{
    __shared__ __align__(16) char smA[32 * 256 * 4];  // [32][256] fp32 [h|m]
    __shared__ unsigned short znb[32 * 128];          // z_n bf16, 8KB
    const int t = threadIdx.x;
    const int n0 = blockIdx.x * 32;

    // build A = [h | m] fp32
#pragma unroll
    for (int i = 0; i < 8; i++) {
        int c = i * 256 + t;              // 0..2047
        int nd = c >> 6, q = c & 63;
        const float* src = (q < 32) ? (h_cur + (size_t)(n0 + nd) * 128 + q * 4)
                                    : (m + (size_t)(n0 + nd) * 128 + (q - 32) * 4);
        f4 v = *reinterpret_cast<const f4*>(src);
        int dst = (nd * 1024 + q * 16) ^ ((nd & 7) << 5);
        *reinterpret_cast<f4*>(smA + dst) = v;
    }
    __syncthreads();

    const int lane = t & 63, w = t >> 6;
    const int wm = w & 1, wn = w >> 1;
    const int lr = lane & 15, lg = lane >> 4;
    const int nA = wm * 16 + lr;
    const int nC0 = wm * 16 + lg * 4;

    // GEMM1: z = relu([h|m] @ nW1 + nb1), A hi/lo
    us8 afh[8], afl[8];
#pragma unroll
    for (int ks = 0; ks < 8; ks++) {
        int base = (nA * 1024 + ks * 128 + lg * 32) ^ ((nA & 7) << 5);
        f4 a0 = *reinterpret_cast<const f4*>(smA + base);
        f4 a1 = *reinterpret_cast<const f4*>(smA + base + 16);
        split8(a0, a1, afh[ks], afl[ks]);
    }
#pragma unroll
    for (int nt = 0; nt < 4; nt++) {
        int feat = wn * 64 + nt * 16 + lr;
        const unsigned short* bp = nW1T + feat * 256 + lg * 8;
        f4 a = {0.f, 0.f, 0.f, 0.f};
#pragma unroll
        for (int ks = 0; ks < 8; ks++) {
            us8 b = *reinterpret_cast<const us8*>(bp + ks * 32);
            a = mfma16(afh[ks], b, a);
            a = mfma16(afl[ks], b, a);
        }
        float bias = nb1[feat];
#pragma unroll
        for (int r = 0; r < 4; r++) {
            float z = a[r] + bias;
            z = z > 0.f ? z : 0.f;
            int nd = nC0 + r;
            int ad = (nd * 256 + feat * 2) ^ ((nd & 7) << 4);
            *reinterpret_cast<unsigned short*>(reinterpret_cast<char*>(znb) + ad) = f2bf(z);
        }
    }
    __syncthreads();

    // GEMM2: h = h + (z @ nW2 + nb2); write h_cur + packed hi/lo
    us8 af2[4];
#pragma unroll
    for (int ks = 0; ks < 4; ks++) {
        int ad = (nA * 256 + ks * 64 + lg * 16) ^ ((nA & 7) << 4);
        af2[ks] = *reinterpret_cast<const us8*>(reinterpret_cast<char*>(znb) + ad);
    }
#pragma unroll
    for (int nt = 0; nt < 4; nt++) {
        int feat = wn * 64 + nt * 16 + lr;
        const unsigned short* bp = nW2T + feat * 128 + lg * 8;
        f4 a = {0.f, 0.f, 0.f, 0.f};
#pragma unroll
        for (int ks = 0; ks < 4; ks++)
            a = mfma16(af2[ks], *reinterpret_cast<const us8*>(bp + ks * 32), a);
        float bias = nb2[feat];
#pragma unroll
        for (int r = 0; r < 4; r++) {
            int nd = nC0 + r;
            int gi = (n0 + nd) * 128 + feat;
            float v = h_cur[gi] + a[r] + bias;
            h_cur[gi] = v;
            unsigned short hh = f2bf(v);
            h_pk[(size_t)(n0 + nd) * 256 + feat] = hh;
            h_pk[(size_t)(n0 + nd) * 256 + 128 + feat] = f2bf(v - bf2f(hh));
        }
    }

    // x += xu ; zero xu ; zero m for next layer (m reads happened pre-barrier)
    if (t < 96) {
        int nd = t / 3, d = t - nd * 3;
        int gi = (n0 + nd) * 3 + d;
        x_cur[gi] += xu[gi];
        xu[gi] = 0.f;
    }
#pragma unroll
    for (int i = 0; i < 16; i++) m[(size_t)n0 * 128 + i * 256 + t] = 0.f;
}

__global__ void __launch_bounds__(256) writeout(
    const float* __restrict__ h_cur, const float* __restrict__ x_cur,
    float* __restrict__ out)
{
    int i = blockIdx.x * 256 + threadIdx.x;
    if (i < NN * 128) out[i] = h_cur[i];
    else {
        int j = i - NN * 128;
        if (j < NN * 3) out[i] = x_cur[j];
    }
}

extern "C" void kernel_launch(void* const* d_in, const int* in_sizes, int n_in,
                              void* d_out, int out_size, void* d_ws, size_t ws_size,
                              hipStream_t stream)
{
    (void)in_sizes; (void)n_in; (void)out_size; (void)ws_size;
    const float* h_in = (const float*)d_in[0];
    const float* x_in = (const float*)d_in[1];
    const int* eidx   = (const int*)d_in[2];
    const float* embW = (const float*)d_in[3];
    const float* embB = (const float*)d_in[4];
    const float* eW1  = (const float*)d_in[5];
    const float* eb1  = (const float*)d_in[6];
    const float* eW2  = (const float*)d_in[7];
    const float* eb2  = (const float*)d_in[8];
    const float* nW1  = (const float*)d_in[9];
    const float* nb1  = (const float*)d_in[10];
    const float* nW2  = (const float*)d_in[11];
    const float* nb2  = (const float*)d_in[12];
    const float* cW1  = (const float*)d_in[13];
    const float* cb1  = (const float*)d_in[14];
    const float* cW2  = (const float*)d_in[15];
    const float* cb2  = (const float*)d_in[16];

    char* ws = (char*)d_ws;
    size_t off = 0;
    auto alloc = [&](size_t bytes) -> char* {
        char* p = ws + off;
        off += (bytes + 255) & ~size_t(255);
        return p;
    };
    float* h_cur = (float*)alloc((size_t)NN * 128 * 4);
    float* m     = (float*)alloc((size_t)NN * 128 * 4);
    unsigned short* h_pk = (unsigned short*)alloc((size_t)NN * 256 * 2);
    float* x_cur = (float*)alloc((size_t)NN * 3 * 4);
    float* xu    = (float*)alloc((size_t)NN * 3 * 4);
    unsigned short* eW1T = (unsigned short*)alloc(128 * 256 * 2);
    unsigned short* eW2T = (unsigned short*)alloc(128 * 128 * 2);
    unsigned short* nW1T = (unsigned short*)alloc(128 * 256 * 2);
    unsigned short* nW2T = (unsigned short*)alloc(128 * 128 * 2);
    unsigned short* cW1T = (unsigned short*)alloc(128 * 128 * 2);
    float* ew1last = (float*)alloc(128 * 4);
    int* counters = (int*)alloc((size_t)2 * NN * 4);  // deg | cursor, one block
    int* deg    = counters;
    int* cursor = counters + NN;
    int* offs   = (int*)alloc((size_t)(NN + 1) * 4);
    int* srow   = (int*)alloc((size_t)NE * 4);
    int* scol   = (int*)alloc((size_t)NE * 4);

    // CSR sort of edges by row (once per launch)
    zero_kernel<<<(2 * NN + 255) / 256, 256, 0, stream>>>(counters, 2 * NN);
    prep_weights<<<449, 256, 0, stream>>>(eW1, eW2, nW1, nW2, cW1,
                                          eW1T, eW2T, nW1T, nW2T, cW1T, ew1last);
    embed_init<<<NN, 128, 0, stream>>>(h_in, x_in, embW, embB,
                                       h_cur, h_pk, x_cur, m, xu);
    hist_kernel<<<(NE + 255) / 256, 256, 0, stream>>>(eidx, deg);
    scan_kernel<<<1, 1024, 0, stream>>>(deg, offs);
    scatter_kernel<<<(NE + 255) / 256, 256, 0, stream>>>(eidx, offs, cursor, srow, scol);

    for (int l = 0; l < 2; l++) {
        edge_kernel<<<NE / 32, 256, 0, stream>>>(srow, scol, h_pk, x_cur,
                                                 eW1T, eW2T, cW1T, ew1last,
                                                 eb1, eb2, cb1, cb2, cW2, m, xu);
        node_kernel<<<NN / 32, 256, 0, stream>>>(nW1T, nW2T, nb1, nb2,
                                                 h_cur, h_pk, m, x_cur, xu);
    }
    writeout<<<(NN * 128 + NN * 3 + 255) / 256, 256, 0, stream>>>(h_cur, x_cur, (float*)d_out);
}

// Round 8
// 1145.730 us; speedup vs baseline: 1.5878x; 1.5878x over previous
//
#include <hip/hip_runtime.h>

#define NN 20000
#define NE 640000

typedef __attribute__((ext_vector_type(4))) float f4;
typedef __attribute__((ext_vector_type(8))) unsigned short us8;
typedef __attribute__((ext_vector_type(8))) __bf16 bf8;
typedef __attribute__((ext_vector_type(4))) int i4;

__device__ __forceinline__ unsigned short f2bf(float f) {
    union { float f; unsigned int u; } v; v.f = f;
    unsigned int u = v.u;
    return (unsigned short)((u + 0x7FFFu + ((u >> 16) & 1u)) >> 16);
}
__device__ __forceinline__ float bf2f(unsigned short b) {
    union { unsigned int u; float f; } v; v.u = ((unsigned int)b) << 16; return v.f;
}
__device__ __forceinline__ f4 mfma16(us8 a, us8 b, f4 c) {
    return __builtin_amdgcn_mfma_f32_16x16x32_bf16(
        __builtin_bit_cast(bf8, a), __builtin_bit_cast(bf8, b), c, 0, 0, 0);
}
__device__ __forceinline__ void split8(f4 a0, f4 a1, us8& h, us8& l) {
#pragma unroll
    for (int j = 0; j < 4; j++) {
        unsigned short hb = f2bf(a0[j]); h[j] = hb; l[j] = f2bf(a0[j] - bf2f(hb));
        unsigned short hb2 = f2bf(a1[j]); h[4 + j] = hb2; l[4 + j] = f2bf(a1[j] - bf2f(hb2));
    }
}

// ---------------- weight prep ----------------
// pqW[f][k] (256x128): f<128 -> eW1[k][f] (P weights); f>=128 -> eW1[128+k][f-128] (Q)
__global__ void __launch_bounds__(256) prep_weights(
    const float* __restrict__ eW1, const float* __restrict__ eW2,
    const float* __restrict__ nW1, const float* __restrict__ nW2,
    const float* __restrict__ cW1,
    unsigned short* __restrict__ pqW, unsigned short* __restrict__ eW2T,
    unsigned short* __restrict__ nW1T, unsigned short* __restrict__ nW2T,
    unsigned short* __restrict__ cW1T, float* __restrict__ ew1last)
{
    int i = blockIdx.x * 256 + threadIdx.x;
    if (i < 32768) {
        int f = i >> 7, k = i & 127;
        float v = (f < 128) ? eW1[k * 128 + f] : eW1[(128 + k) * 128 + (f - 128)];
        pqW[i] = f2bf(v); return;
    }
    i -= 32768;
    if (i < 16384) { int f = i >> 7, k = i & 127; eW2T[i] = f2bf(eW2[k * 128 + f]); return; }
    i -= 16384;
    if (i < 32768) { int f = i >> 8, k = i & 255; nW1T[i] = f2bf(nW1[k * 128 + f]); return; }
    i -= 32768;
    if (i < 16384) { int f = i >> 7, k = i & 127; nW2T[i] = f2bf(nW2[k * 128 + f]); return; }
    i -= 16384;
    if (i < 16384) { int f = i >> 7, k = i & 127; cW1T[i] = f2bf(cW1[k * 128 + f]); return; }
    i -= 16384;
    if (i < 128) { ew1last[i] = eW1[256 * 128 + i]; }
}

// ---------------- embedding + state init ----------------
__global__ void __launch_bounds__(128) embed_init(
    const float* __restrict__ h_in, const float* __restrict__ x_in,
    const float* __restrict__ embW, const float* __restrict__ embB,
    float* __restrict__ h_cur, float* __restrict__ x_cur,
    float* __restrict__ m, float* __restrict__ xu)
{
    int n = blockIdx.x, f = threadIdx.x;
    float acc = embB[f];
#pragma unroll
    for (int p = 0; p < 16; p++) acc += h_in[n * 16 + p] * embW[p * 128 + f];
    h_cur[n * 128 + f] = acc;
    m[n * 128 + f] = 0.f;
    if (f < 3) { x_cur[n * 3 + f] = x_in[n * 3 + f]; xu[n * 3 + f] = 0.f; }
}

// ---------------- CSR sort ----------------
__global__ void __launch_bounds__(256) zero_kernel(int* __restrict__ p, int n) {
    int i = blockIdx.x * 256 + threadIdx.x;
    if (i < n) p[i] = 0;
}

__global__ void __launch_bounds__(256) hist_kernel(const int* __restrict__ eidx,
                                                   int* __restrict__ deg) {
    int e = blockIdx.x * 256 + threadIdx.x;
    if (e < NE) atomicAdd(&deg[eidx[e]], 1);
}

__global__ void __launch_bounds__(1024) scan_kernel(const int* __restrict__ deg,
                                                    int* __restrict__ offs) {
    __shared__ int ssum[1024];
    const int t = threadIdx.x;
    const int base = t * 20;
    int loc[20];
    int s = 0;
#pragma unroll
    for (int i = 0; i < 20; i++) {
        int v = (base + i < NN) ? deg[base + i] : 0;
        loc[i] = s; s += v;
    }
    ssum[t] = s;
    __syncthreads();
    for (int d = 1; d < 1024; d <<= 1) {
        int v = (t >= d) ? ssum[t - d] : 0;
        __syncthreads();
        ssum[t] += v;
        __syncthreads();
    }
    int excl = (t == 0) ? 0 : ssum[t - 1];
#pragma unroll
    for (int i = 0; i < 20; i++)
        if (base + i < NN) offs[base + i] = excl + loc[i];
    if (t == 1023) offs[NN] = ssum[1023];
}

__global__ void __launch_bounds__(256) scatter_kernel(
    const int* __restrict__ eidx, const int* __restrict__ offs,
    int* __restrict__ cursor, int* __restrict__ srow, int* __restrict__ scol)
{
    int e = blockIdx.x * 256 + threadIdx.x;
    if (e >= NE) return;
    int r = eidx[e];
    int pos = offs[r] + atomicAdd(&cursor[r], 1);
    srow[pos] = r;
    scol[pos] = eidx[NE + e];
}

// ---------------- pq_kernel: P|Q = h @ pqW^T  (per node, fp32 out) ----------
// 32 nodes/block, 256 threads, 4 waves (each wave: 64 of 256 out-feats)
__global__ void __launch_bounds__(256, 2) pq_kernel(
    const float* __restrict__ h_cur, const unsigned short* __restrict__ pqW,
    float* __restrict__ pq)
{
    __shared__ __align__(16) char smA[32 * 128 * 4];  // 16KB fp32 h tile
    const int t = threadIdx.x;
    const int n0 = blockIdx.x * 32;

#pragma unroll
    for (int i = 0; i < 4; i++) {
        int c = i * 256 + t;              // 0..1023 f4-chunks
        int nd = c >> 5, q = c & 31;
        f4 v = *reinterpret_cast<const f4*>(h_cur + (size_t)(n0 + nd) * 128 + q * 4);
        int dst = (nd * 512 + q * 16) ^ ((nd & 7) << 5);
        *reinterpret_cast<f4*>(smA + dst) = v;
    }
    __syncthreads();

    const int lane = t & 63, w = t >> 6;
    const int lr = lane & 15, lg = lane >> 4;

    us8 ah[2][4], al[2][4];
#pragma unroll
    for (int rb = 0; rb < 2; rb++) {
        int row = rb * 16 + lr;
#pragma unroll
        for (int ks = 0; ks < 4; ks++) {
            int base = (row * 512 + ks * 128 + lg * 32) ^ ((row & 7) << 5);
            f4 a0 = *reinterpret_cast<const f4*>(smA + base);
            f4 a1 = *reinterpret_cast<const f4*>(smA + base + 16);
            split8(a0, a1, ah[rb][ks], al[rb][ks]);
        }
    }
#pragma unroll
    for (int rb = 0; rb < 2; rb++) {
#pragma unroll
        for (int nt = 0; nt < 4; nt++) {
            int feat = w * 64 + nt * 16 + lr;
            const unsigned short* bp = pqW + feat * 128 + lg * 8;
            f4 a = {0.f, 0.f, 0.f, 0.f};
#pragma unroll
            for (int ks = 0; ks < 4; ks++) {
                us8 b = *reinterpret_cast<const us8*>(bp + ks * 32);
                a = mfma16(ah[rb][ks], b, a);
                a = mfma16(al[rb][ks], b, a);
            }
#pragma unroll
            for (int r = 0; r < 4; r++) {
                int n = n0 + rb * 16 + lg * 4 + r;
                pq[(size_t)n * 256 + feat] = a[r];
            }
        }
    }
}

// ---------------- fused edge kernel --------------------------------------
// 16 edges/block, 256 threads, 4 waves; z1 via gather P[row]+Q[col] (no GEMM1).
// LDS: z1h [0,4K) (z3 overlays later), z1l [4K,8K), e_ij fp32 [8K,16K).
__global__ void __launch_bounds__(256, 8) edge_kernel(
    const int* __restrict__ srow, const int* __restrict__ scol,
    const float* __restrict__ pq, const float* __restrict__ x_cur,
    const unsigned short* __restrict__ eW2T, const unsigned short* __restrict__ cW1T,
    const float* __restrict__ ew1last,
    const float* __restrict__ eb1, const float* __restrict__ eb2,
    const float* __restrict__ cb1, const float* __restrict__ cb2,
    const float* __restrict__ cW2,
    float* __restrict__ m, float* __restrict__ xu)
{
    __shared__ __align__(16) char sm[16384];
    __shared__ int rowS[16];
    __shared__ int colS[16];
    __shared__ float rpS[16][3];
    __shared__ float rdS[16];

    const int t = threadIdx.x;
    const int e0 = blockIdx.x * 16;

    if (t < 16) {
        int r = srow[e0 + t], c = scol[e0 + t];
        rowS[t] = r; colS[t] = c;
        float dx = x_cur[r * 3 + 0] - x_cur[c * 3 + 0];
        float dy = x_cur[r * 3 + 1] - x_cur[c * 3 + 1];
        float dz = x_cur[r * 3 + 2] - x_cur[c * 3 + 2];
        rpS[t][0] = dx; rpS[t][1] = dy; rpS[t][2] = dz;
        rdS[t] = dx * dx + dy * dy + dz * dz;
    }
    __syncthreads();

    // ---- phase A: z1 = relu(P[row] + Q[col] + rd*wl + b), split hi/lo ----
    {
        const int e = t >> 4, s = t & 15;        // edge, feat-oct (8 feats)
        const int r = rowS[e], c = colS[e];
        const float rd = rdS[e];
        const float* pr = pq + (size_t)r * 256 + s * 8;
        const float* qc = pq + (size_t)c * 256 + 128 + s * 8;
        f4 p0 = *reinterpret_cast<const f4*>(pr);
        f4 p1 = *reinterpret_cast<const f4*>(pr + 4);
        f4 q0 = *reinterpret_cast<const f4*>(qc);
        f4 q1 = *reinterpret_cast<const f4*>(qc + 4);
        f4 b0 = *reinterpret_cast<const f4*>(eb1 + s * 8);
        f4 b1 = *reinterpret_cast<const f4*>(eb1 + s * 8 + 4);
        f4 w0 = *reinterpret_cast<const f4*>(ew1last + s * 8);
        f4 w1 = *reinterpret_cast<const f4*>(ew1last + s * 8 + 4);
        f4 z0, z1;
#pragma unroll
        for (int j = 0; j < 4; j++) {
            float a = p0[j] + q0[j] + rd * w0[j] + b0[j];
            float b = p1[j] + q1[j] + rd * w1[j] + b1[j];
            z0[j] = a > 0.f ? a : 0.f;
            z1[j] = b > 0.f ? b : 0.f;
        }
        us8 zh, zl;
        split8(z0, z1, zh, zl);
        int ad = (e * 256 + s * 16) ^ ((e & 7) << 4);
        *reinterpret_cast<us8*>(sm + ad) = zh;
        *reinterpret_cast<us8*>(sm + 4096 + ad) = zl;
    }
    __syncthreads();

    const int lane = t & 63, w = t >> 6;
    const int lr = lane & 15, lg = lane >> 4;
    const int eC0 = lg * 4;                      // C-frag edge base

    // ---- phase B: GEMM2  e_ij = z1 @ eW2 + eb2 (hi/lo) -> fp32 LDS ----
    {
        us8 a2h[4], a2l[4];
#pragma unroll
        for (int ks = 0; ks < 4; ks++) {
            int ad = (lr * 256 + ks * 64 + lg * 16) ^ ((lr & 7) << 4);
            a2h[ks] = *reinterpret_cast<const us8*>(sm + ad);
            a2l[ks] = *reinterpret_cast<const us8*>(sm + 4096 + ad);
        }
#pragma unroll
        for (int nt = 0; nt < 2; nt++) {
            int feat = w * 32 + nt * 16 + lr;
            const unsigned short* bp = eW2T + feat * 128 + lg * 8;
            f4 a = {0.f, 0.f, 0.f, 0.f};
#pragma unroll
            for (int ks = 0; ks < 4; ks++) {
                us8 b = *reinterpret_cast<const us8*>(bp + ks * 32);
                a = mfma16(a2h[ks], b, a);
                a = mfma16(a2l[ks], b, a);
            }
            float bias = eb2[feat];
#pragma unroll
            for (int r = 0; r < 4; r++) {
                int e = eC0 + r;
                int ad = 8192 + ((e * 512 + feat * 4) ^ ((e & 7) << 5));
                *reinterpret_cast<float*>(sm + ad) = a[r] + bias;
            }
        }
    }
    __syncthreads();

    // ---- phase C: m-accum (waves 0-1) + GEMM3 (all waves) ----
    if (t < 128) {
        int feat = t;
        float acc = 0.f;
        int prow = rowS[0];
#pragma unroll
        for (int e = 0; e < 16; e++) {
            int r = rowS[e];
            if (r != prow) {
                atomicAdd(&m[(size_t)prow * 128 + feat], acc);
                acc = 0.f; prow = r;
            }
            int ad = 8192 + ((e * 512 + feat * 4) ^ ((e & 7) << 5));
            acc += *reinterpret_cast<const float*>(sm + ad);
        }
        atomicAdd(&m[(size_t)prow * 128 + feat], acc);
    }
    {
        us8 af3[4];
#pragma unroll
        for (int ks = 0; ks < 4; ks++) {
            int base = 8192 + ((lr * 512 + ks * 128 + lg * 32) ^ ((lr & 7) << 5));
            f4 a0 = *reinterpret_cast<const f4*>(sm + base);
            f4 a1 = *reinterpret_cast<const f4*>(sm + base + 16);
            us8 h;
#pragma unroll
            for (int j = 0; j < 4; j++) { h[j] = f2bf(a0[j]); h[4 + j] = f2bf(a1[j]); }
            af3[ks] = h;
        }
#pragma unroll
        for (int nt = 0; nt < 2; nt++) {
            int feat = w * 32 + nt * 16 + lr;
            const unsigned short* bp = cW1T + feat * 128 + lg * 8;
            f4 a = {0.f, 0.f, 0.f, 0.f};
#pragma unroll
            for (int ks = 0; ks < 4; ks++)
                a = mfma16(af3[ks], *reinterpret_cast<const us8*>(bp + ks * 32), a);
            float bias = cb1[feat];
#pragma unroll
            for (int r = 0; r < 4; r++) {
                float z = a[r] + bias;
                z = z > 0.f ? z : 0.f;
                int e = eC0 + r;
                int ad = (e * 256 + feat * 2) ^ ((e & 7) << 4);   // z3 overlays z1h
                *reinterpret_cast<unsigned short*>(sm + ad) = f2bf(z);
            }
        }
    }
    __syncthreads();

    // ---- phase D: alpha = z3 @ cW2 + cb2 ; xu atomics (waves 0-1) ----
    if (t < 128) {
        int e = t >> 3, s = t & 7;
        float sum = 0.f;
#pragma unroll
        for (int hf = 0; hf < 2; hf++) {
            int ad = (e * 256 + s * 32 + hf * 16) ^ ((e & 7) << 4);
            us8 v = *reinterpret_cast<const us8*>(sm + ad);
#pragma unroll
            for (int j = 0; j < 8; j++)
                sum += bf2f((unsigned short)v[j]) * cW2[s * 16 + hf * 8 + j];
        }
        sum += __shfl_xor(sum, 1, 64);
        sum += __shfl_xor(sum, 2, 64);
        sum += __shfl_xor(sum, 4, 64);
        if (s == 0) {
            float alpha = sum + cb2[0];
            int r = rowS[e];
            atomicAdd(&xu[r * 3 + 0], alpha * rpS[e][0]);
            atomicAdd(&xu[r * 3 + 1], alpha * rpS[e][1]);
            atomicAdd(&xu[r * 3 + 2], alpha * rpS[e][2]);
        }
    }
}

// ---------------- node update kernel (fp32 A via hi/lo MFMA) ----------------
__global__ void __launch_bounds__(256, 4) node_kernel(
    const unsigned short* __restrict__ nW1T, const unsigned short* __restrict__ nW2T,
    const float* __restrict__ nb1, const float* __restrict__ nb2,
    float* __restrict__ h_cur,
    float* __restrict__ m, float* __restrict__ x_cur, float* __restrict__ xu)
{
    __shared__ __align__(16) char smA[32 * 256 * 4];  // [32][256] fp32 [h|m]
    __shared__ unsigned short znb[32 * 128];
    const int t = threadIdx.x;
    const int n0 = blockIdx.x * 32;

#pragma unroll
    for (int i = 0; i < 8; i++) {
        int c = i * 256 + t;
        int nd = c >> 6, q = c & 63;
        const float* src = (q < 32) ? (h_cur + (size_t)(n0 + nd) * 128 + q * 4)
                                    : (m + (size_t)(n0 + nd) * 128 + (q - 32) * 4);
        f4 v = *reinterpret_cast<const f4*>(src);
        int dst = (nd * 1024 + q * 16) ^ ((nd & 7) << 5);
        *reinterpret_cast<f4*>(smA + dst) = v;
    }
    __syncthreads();

    const int lane = t & 63, w = t >> 6;
    const int wm = w & 1, wn = w >> 1;
    const int lr = lane & 15, lg = lane >> 4;
    const int nA = wm * 16 + lr;
    const int nC0 = wm * 16 + lg * 4;

    us8 afh[8], afl[8];
#pragma unroll
    for (int ks = 0; ks < 8; ks++) {
        int base = (nA * 1024 + ks * 128 + lg * 32) ^ ((nA & 7) << 5);
        f4 a0 = *reinterpret_cast<const f4*>(smA + base);
        f4 a1 = *reinterpret_cast<const f4*>(smA + base + 16);
        split8(a0, a1, afh[ks], afl[ks]);
    }
#pragma unroll
    for (int nt = 0; nt < 4; nt++) {
        int feat = wn * 64 + nt * 16 + lr;
        const unsigned short* bp = nW1T + feat * 256 + lg * 8;
        f4 a = {0.f, 0.f, 0.f, 0.f};
#pragma unroll
        for (int ks = 0; ks < 8; ks++) {
            us8 b = *reinterpret_cast<const us8*>(bp + ks * 32);
            a = mfma16(afh[ks], b, a);
            a = mfma16(afl[ks], b, a);
        }
        float bias = nb1[feat];
#pragma unroll
        for (int r = 0; r < 4; r++) {
            float z = a[r] + bias;
            z = z > 0.f ? z : 0.f;
            int nd = nC0 + r;
            int ad = (nd * 256 + feat * 2) ^ ((nd & 7) << 4);
            *reinterpret_cast<unsigned short*>(reinterpret_cast<char*>(znb) + ad) = f2bf(z);
        }
    }
    __syncthreads();

    us8 af2[4];
#pragma unroll
    for (int ks = 0; ks < 4; ks++) {
        int ad = (nA * 256 + ks * 64 + lg * 16) ^ ((nA & 7) << 4);
        af2[ks] = *reinterpret_cast<const us8*>(reinterpret_cast<char*>(znb) + ad);
    }
#pragma unroll
    for (int nt = 0; nt < 4; nt++) {
        int feat = wn * 64 + nt * 16 + lr;
        const unsigned short* bp = nW2T + feat * 128 + lg * 8;
        f4 a = {0.f, 0.f, 0.f, 0.f};
#pragma unroll
        for (int ks = 0; ks < 4; ks++)
            a = mfma16(af2[ks], *reinterpret_cast<const us8*>(bp + ks * 32), a);
        float bias = nb2[feat];
#pragma unroll
        for (int r = 0; r < 4; r++) {
            int nd = nC0 + r;
            int gi = (n0 + nd) * 128 + feat;
            h_cur[gi] = h_cur[gi] + a[r] + bias;
        }
    }

    if (t < 96) {
        int nd = t / 3, d = t - nd * 3;
        int gi = (n0 + nd) * 3 + d;
        x_cur[gi] += xu[gi];
        xu[gi] = 0.f;
    }
#pragma unroll
    for (int i = 0; i < 16; i++) m[(size_t)n0 * 128 + i * 256 + t] = 0.f;
}

__global__ void __launch_bounds__(256) writeout(
    const float* __restrict__ h_cur, const float* __restrict__ x_cur,
    float* __restrict__ out)
{
    int i = blockIdx.x * 256 + threadIdx.x;
    if (i < NN * 128) out[i] = h_cur[i];
    else {
        int j = i - NN * 128;
        if (j < NN * 3) out[i] = x_cur[j];
    }
}

extern "C" void kernel_launch(void* const* d_in, const int* in_sizes, int n_in,
                              void* d_out, int out_size, void* d_ws, size_t ws_size,
                              hipStream_t stream)
{
    (void)in_sizes; (void)n_in; (void)out_size; (void)ws_size;
    const float* h_in = (const float*)d_in[0];
    const float* x_in = (const float*)d_in[1];
    const int* eidx   = (const int*)d_in[2];
    const float* embW = (const float*)d_in[3];
    const float* embB = (const float*)d_in[4];
    const float* eW1  = (const float*)d_in[5];
    const float* eb1  = (const float*)d_in[6];
    const float* eW2  = (const float*)d_in[7];
    const float* eb2  = (const float*)d_in[8];
    const float* nW1  = (const float*)d_in[9];
    const float* nb1  = (const float*)d_in[10];
    const float* nW2  = (const float*)d_in[11];
    const float* nb2  = (const float*)d_in[12];
    const float* cW1  = (const float*)d_in[13];
    const float* cb1  = (const float*)d_in[14];
    const float* cW2  = (const float*)d_in[15];
    const float* cb2  = (const float*)d_in[16];

    char* ws = (char*)d_ws;
    size_t off = 0;
    auto alloc = [&](size_t bytes) -> char* {
        char* p = ws + off;
        off += (bytes + 255) & ~size_t(255);
        return p;
    };
    float* h_cur = (float*)alloc((size_t)NN * 128 * 4);
    float* m     = (float*)alloc((size_t)NN * 128 * 4);
    float* pq    = (float*)alloc((size_t)NN * 256 * 4);
    float* x_cur = (float*)alloc((size_t)NN * 3 * 4);
    float* xu    = (float*)alloc((size_t)NN * 3 * 4);
    unsigned short* pqW  = (unsigned short*)alloc(256 * 128 * 2);
    unsigned short* eW2T = (unsigned short*)alloc(128 * 128 * 2);
    unsigned short* nW1T = (unsigned short*)alloc(128 * 256 * 2);
    unsigned short* nW2T = (unsigned short*)alloc(128 * 128 * 2);
    unsigned short* cW1T = (unsigned short*)alloc(128 * 128 * 2);
    float* ew1last = (float*)alloc(128 * 4);
    int* counters = (int*)alloc((size_t)2 * NN * 4);  // deg | cursor
    int* deg    = counters;
    int* cursor = counters + NN;
    int* offs   = (int*)alloc((size_t)(NN + 1) * 4);
    int* srow   = (int*)alloc((size_t)NE * 4);
    int* scol   = (int*)alloc((size_t)NE * 4);

    zero_kernel<<<(2 * NN + 255) / 256, 256, 0, stream>>>(counters, 2 * NN);
    prep_weights<<<449, 256, 0, stream>>>(eW1, eW2, nW1, nW2, cW1,
                                          pqW, eW2T, nW1T, nW2T, cW1T, ew1last);
    embed_init<<<NN, 128, 0, stream>>>(h_in, x_in, embW, embB,
                                       h_cur, x_cur, m, xu);
    hist_kernel<<<(NE + 255) / 256, 256, 0, stream>>>(eidx, deg);
    scan_kernel<<<1, 1024, 0, stream>>>(deg, offs);
    scatter_kernel<<<(NE + 255) / 256, 256, 0, stream>>>(eidx, offs, cursor, srow, scol);
    pq_kernel<<<NN / 32, 256, 0, stream>>>(h_cur, pqW, pq);

    for (int l = 0; l < 2; l++) {
        edge_kernel<<<NE / 16, 256, 0, stream>>>(srow, scol, pq, x_cur,
                                                 eW2T, cW1T, ew1last,
                                                 eb1, eb2, cb1, cb2, cW2, m, xu);
        node_kernel<<<NN / 32, 256, 0, stream>>>(nW1T, nW2T, nb1, nb2,
                                                 h_cur, m, x_cur, xu);
        if (l == 0)
            pq_kernel<<<NN / 32, 256, 0, stream>>>(h_cur, pqW, pq);
    }
    writeout<<<(NN * 128 + NN * 3 + 255) / 256, 256, 0, stream>>>(h_cur, x_cur, (float*)d_out);
}